// Round 7
// baseline (1516.507 us; speedup 1.0000x reference)
//
#include <hip/hip_runtime.h>

// Problem: bs=8, seq=16, hw=32*32=1024, ck=256, cv=3, steps=seq-1=15
// Inputs fp32: k[8][16][1024][256], v[8][16][1024][3], attention[8][16][1024],
//              seq_mask int32[8][16].  Outputs fp32: out_v ++ gt.
//
// R7: single cooperative megakernel (256 blocks x 512 thr, 1 block/CU).
// 15-step scan runs inside one launch with a ws-based grid barrier.
// Rationale: R5->R6 showed per-step time is dominated by inter-dispatch
// overhead (~20-25 us/step), not in-kernel work (~5 us/step arithmetic).
// Per iteration: B = R5 attn body (q-tile regs, p-stream, both mats,
// in-block merge + epilogue incl pv & m_v EMA), then A = kh convert
// (triple-buffered) + m_kh EMA (double-buffered), one grid sync.
#define BS 8
#define SEQ 16
#define HW 1024
#define CK 256
#define CV 3
#define STEPS 15
#define NBLK 256
#define SKP 264   // padded fp16 LDS row stride (256+8)

typedef unsigned short u16;
typedef _Float16 half8 __attribute__((ext_vector_type(8)));  // MFMA A/B frag
typedef float floatx4 __attribute__((ext_vector_type(4)));   // MFMA C/D frag

__device__ __forceinline__ u16 f2h(float f) {
  _Float16 h = (_Float16)f;
  return __builtin_bit_cast(unsigned short, h);
}
__device__ __forceinline__ float h2f(u16 u) {
  _Float16 h = __builtin_bit_cast(_Float16, u);
  return (float)h;
}
__device__ __forceinline__ void cvt16(const float* __restrict__ src,
                                      u16* __restrict__ dst) {
  u16 t[16];
  #pragma unroll
  for (int j = 0; j < 16; j += 4) {
    float4 a = *(const float4*)(src + j);
    t[j] = f2h(a.x); t[j+1] = f2h(a.y); t[j+2] = f2h(a.z); t[j+3] = f2h(a.w);
  }
  *(int4*)dst = *(const int4*)t;
  *(int4*)(dst + 8) = *(const int4*)(t + 8);
}

// ws layout (21.4 MB; ws is 512 MB per round-5/6 fillBuffer evidence)
#define KH_B  ((size_t)BS * HW * CK * 2)          // 4 MB per kh buffer
#define SV_B  ((size_t)BS * HW * CV * 4)          // 96 KB per small buffer
#define MKH_OFF (3 * KH_B)
#define MV_OFF  (5 * KH_B)
#define PV_OFF  (5 * KH_B + 2 * SV_B)
#define BAR_OFF (5 * KH_B + 4 * SV_B)

__global__ void init_bar(unsigned* bar) { bar[0] = 0u; bar[1] = 0u; }

__device__ __forceinline__ void gsync(unsigned* cnt, unsigned* gen, unsigned lg) {
  __syncthreads();
  if (threadIdx.x == 0) {
    __threadfence();
    if (atomicAdd(cnt, 1u) == NBLK - 1u) {
      atomicExch(cnt, 0u);
      __threadfence();
      atomicAdd(gen, 1u);
    } else {
      while (atomicAdd(gen, 0u) <= lg) __builtin_amdgcn_s_sleep(2);
    }
  }
  __threadfence();
  __syncthreads();
}

__global__ __launch_bounds__(512, 2) void mega(
    const float* __restrict__ k, const float* __restrict__ v,
    const float* __restrict__ att, const int* __restrict__ seq_mask,
    float* __restrict__ out, char* __restrict__ ws)
{
  __shared__ u16 Kq[32 * SKP];       // q-tile fp16 (16.9 KB)
  __shared__ float Mg[8][2][32][5];  // per-wave partials (10.2 KB)

  u16* khs[3] = {(u16*)ws, (u16*)(ws + KH_B), (u16*)(ws + 2 * KH_B)};
  u16* mkhs[2] = {(u16*)(ws + MKH_OFF), (u16*)(ws + MKH_OFF + KH_B)};
  float* mvs[2] = {(float*)(ws + MV_OFF), (float*)(ws + MV_OFF + SV_B)};
  float* pvs[2] = {(float*)(ws + PV_OFF), (float*)(ws + PV_OFF + SV_B)};
  unsigned* bar = (unsigned*)(ws + BAR_OFF);

  const int bid = blockIdx.x;
  const int lb = bid & 7;        // batch <-> XCD affinity (bid % 8)
  const int q0 = (bid >> 3) * 32;
  const int tid = threadIdx.x;
  const int w = tid >> 6, lane = tid & 63;
  const int r = lane & 15, rg = lane >> 4;
  unsigned lg = 0;

  // ================= prologue =================
  { // gt = v[:,1:]  (256 blocks x 1440 elements)
    const int n = BS * STEPS * HW * CV;          // 368,640 = 256*1440
    int base = bid * 1440;
    for (int j = tid; j < 1440; j += 512) {
      int idx = base + j;
      int b = idx / (STEPS * HW * CV);
      int rr0 = idx - b * (STEPS * HW * CV);
      int ii = rr0 / (HW * CV);
      int rr = rr0 - ii * (HW * CV);
      out[n + idx] = v[(long)(b * SEQ + ii + 1) * (HW * CV) + rr];
    }
  }
  { // kh0, kh1 convert + mkh0 = g0*kh0 for rows [q0,q0+32)
    const int pl = tid >> 4, sc = tid & 15;
    const int p = q0 + pl;
    float a0 = att[(long)(lb * SEQ) * HW + p];
    float g0 = 1.0f / (1.0f + __expf(-a0));
    const float* s0 = k + ((long)(lb * SEQ + 0) * HW + p) * CK + sc * 16;
    const float* s1 = k + ((long)(lb * SEQ + 1) * HW + p) * CK + sc * 16;
    long off = ((long)lb * HW + p) * CK + sc * 16;
    u16 t0[16], tm[16];
    #pragma unroll
    for (int j = 0; j < 16; j += 4) {
      float4 a = *(const float4*)(s0 + j);
      t0[j] = f2h(a.x); t0[j+1] = f2h(a.y); t0[j+2] = f2h(a.z); t0[j+3] = f2h(a.w);
    }
    #pragma unroll
    for (int j = 0; j < 16; ++j) tm[j] = f2h(g0 * h2f(t0[j]));
    *(int4*)(khs[0] + off) = *(const int4*)t0;
    *(int4*)(khs[0] + off + 8) = *(const int4*)(t0 + 8);
    *(int4*)(mkhs[0] + off) = *(const int4*)tm;
    *(int4*)(mkhs[0] + off + 8) = *(const int4*)(tm + 8);
    cvt16(s1, khs[1] + off);
  }
  if (tid < 96) { // pv0 = v[:,0], mv0 = g0*pv0 for rows [q0,q0+32)
    int p = q0 + tid / 3, c = tid % 3;
    float a0 = att[(long)(lb * SEQ) * HW + p];
    float g0 = 1.0f / (1.0f + __expf(-a0));
    float pvv = v[((long)lb * SEQ * HW + p) * CV + c];
    long o = ((long)lb * HW + p) * CV + c;
    pvs[0][o] = pvv;
    mvs[0][o] = g0 * pvv;
  }
  gsync(bar, bar + 1, lg); lg++;

  // ================= main loop =================
  for (int i = 0; i < STEPS; ++i) {
    const u16* khq = khs[(i + 1) % 3] + (long)lb * HW * CK;  // q-side k[:,i+1]
    const u16* khp = khs[i % 3] + (long)lb * HW * CK;        // p-side k[:,i]
    const u16* mkp = mkhs[i & 1] + (long)lb * HW * CK;       // m_k (post EMA_i)
    const float* pvc = pvs[i & 1] + (long)lb * HW * CV;
    const float* mvc = mvs[i & 1] + (long)lb * HW * CV;

    { // stage q-tile: 1024 16B-chunks over 512 threads
      #pragma unroll
      for (int j = 0; j < 2; ++j) {
        int c = tid + j * 512;
        int row = c >> 5, off = (c & 31) * 8;
        *(int4*)&Kq[row * SKP + off] = *(const int4*)(khq + (long)(q0 + row) * CK + off);
      }
    }
    __syncthreads();

    // B fragments (q-tile) in registers: 2 q-subtiles x 8 k-steps (64 VGPR)
    half8 Bq[2][8];
    #pragma unroll
    for (int qi = 0; qi < 2; ++qi)
      #pragma unroll
      for (int kk = 0; kk < 8; ++kk)
        Bq[qi][kk] = *(const half8*)&Kq[(qi * 16 + r) * SKP + kk * 32 + rg * 8];

    float mx[2][2], l[2][2], acc[2][2][3];
    #pragma unroll
    for (int m = 0; m < 2; ++m)
      #pragma unroll
      for (int qi = 0; qi < 2; ++qi) {
        mx[m][qi] = -1e30f; l[m][qi] = 0.f;
        acc[m][qi][0] = acc[m][qi][1] = acc[m][qi][2] = 0.f;
      }

    for (int pc = 0; pc < 4; ++pc) {
      const int p0 = w * 128 + pc * 32;
      #pragma unroll
      for (int mat = 0; mat < 2; ++mat) {
        const u16* Ab = mat ? mkp : khp;
        const float* PV = mat ? mvc : pvc;
        #pragma unroll
        for (int pi = 0; pi < 2; ++pi) {
          const int pr = p0 + pi * 16;
          float Vv[4][3];
          #pragma unroll
          for (int j = 0; j < 4; ++j) {
            const float* vp = PV + (long)(pr + rg * 4 + j) * CV;
            Vv[j][0] = vp[0]; Vv[j][1] = vp[1]; Vv[j][2] = vp[2];
          }
          half8 A[8];
          #pragma unroll
          for (int kk = 0; kk < 8; ++kk)
            A[kk] = *(const half8*)(Ab + (long)(pr + r) * CK + kk * 32 + rg * 8);
          floatx4 c0 = {0.f, 0.f, 0.f, 0.f}, c1 = {0.f, 0.f, 0.f, 0.f};
          #pragma unroll
          for (int kk = 0; kk < 8; ++kk) {
            c0 = __builtin_amdgcn_mfma_f32_16x16x32_f16(A[kk], Bq[0][kk], c0, 0, 0, 0);
            c1 = __builtin_amdgcn_mfma_f32_16x16x32_f16(A[kk], Bq[1][kk], c1, 0, 0, 0);
          }
          #pragma unroll
          for (int qi = 0; qi < 2; ++qi) {
            floatx4 cc = qi ? c1 : c0;
            float tmax = fmaxf(fmaxf(cc[0], cc[1]), fmaxf(cc[2], cc[3]));
            tmax = fmaxf(tmax, mx[mat][qi]);
            float sc = __expf(mx[mat][qi] - tmax);
            l[mat][qi] *= sc;
            acc[mat][qi][0] *= sc; acc[mat][qi][1] *= sc; acc[mat][qi][2] *= sc;
            #pragma unroll
            for (int j = 0; j < 4; ++j) {
              float e = __expf(cc[j] - tmax);
              l[mat][qi] += e;
              acc[mat][qi][0] = fmaf(e, Vv[j][0], acc[mat][qi][0]);
              acc[mat][qi][1] = fmaf(e, Vv[j][1], acc[mat][qi][1]);
              acc[mat][qi][2] = fmaf(e, Vv[j][2], acc[mat][qi][2]);
            }
            mx[mat][qi] = tmax;
          }
        }
      }
    }

    // merge 4 rowgroup partials (lanes r, r+16, r+32, r+48)
    #pragma unroll
    for (int off = 16; off <= 32; off <<= 1) {
      #pragma unroll
      for (int m = 0; m < 2; ++m)
        #pragma unroll
        for (int qi = 0; qi < 2; ++qi) {
          float m2 = __shfl_xor(mx[m][qi], off);
          float l2 = __shfl_xor(l[m][qi], off);
          float b0s = __shfl_xor(acc[m][qi][0], off);
          float b1s = __shfl_xor(acc[m][qi][1], off);
          float b2s = __shfl_xor(acc[m][qi][2], off);
          float mn = fmaxf(mx[m][qi], m2);
          float e1 = __expf(mx[m][qi] - mn), e2 = __expf(m2 - mn);
          l[m][qi] = l[m][qi] * e1 + l2 * e2;
          acc[m][qi][0] = acc[m][qi][0] * e1 + b0s * e2;
          acc[m][qi][1] = acc[m][qi][1] * e1 + b1s * e2;
          acc[m][qi][2] = acc[m][qi][2] * e1 + b2s * e2;
          mx[m][qi] = mn;
        }
    }
    if (rg == 0) {
      #pragma unroll
      for (int m = 0; m < 2; ++m)
        #pragma unroll
        for (int qi = 0; qi < 2; ++qi) {
          float* d = Mg[w][m][qi * 16 + r];
          d[0] = mx[m][qi]; d[1] = l[m][qi];
          d[2] = acc[m][qi][0]; d[3] = acc[m][qi][1]; d[4] = acc[m][qi][2];
        }
    }
    __syncthreads();

    // cross-wave merge + epilogue: one thread per q-row
    if (tid < 32) {
      const int q = tid;
      float res[2][3];
      #pragma unroll
      for (int m = 0; m < 2; ++m) {
        float M = -1e30f, L = 0.f, A0 = 0.f, A1 = 0.f, A2 = 0.f;
        #pragma unroll
        for (int ww = 0; ww < 8; ++ww) {
          const float* d = Mg[ww][m][q];
          float mn = fmaxf(M, d[0]);
          float e1 = __expf(M - mn), e2 = __expf(d[0] - mn);
          L = L * e1 + d[1] * e2;
          A0 = A0 * e1 + d[2] * e2;
          A1 = A1 * e1 + d[3] * e2;
          A2 = A2 * e1 + d[4] * e2;
          M = mn;
        }
        float iL = 1.0f / L;
        res[m][0] = A0 * iL; res[m][1] = A1 * iL; res[m][2] = A2 * iL;
      }
      const int qg = q0 + q;
      float* ov = out + ((long)(lb * STEPS + i) * HW + qg) * CV;
      float rec[3];
      #pragma unroll
      for (int c = 0; c < CV; ++c) {
        rec[c] = 0.9f * res[0][c] + 0.1f * res[1][c];  // COEF_MEMORY = 0.1
        ov[c] = rec[c];
      }
      if (i < STEPS - 1) {  // pv_{i+1} + m_v EMA for step i+1
        const int maskv = seq_mask[lb * SEQ + i];
        const float* vr = v + ((long)(lb * SEQ + i) * HW + qg) * CV;
        float an = att[(long)(lb * SEQ + i + 1) * HW + qg];
        float gn = 1.0f / (1.0f + __expf(-an)), ogn = 1.0f - gn;
        long o = ((long)lb * HW + qg) * CV;
        float* pn = pvs[(i + 1) & 1];
        float* mn2 = mvs[(i + 1) & 1];
        #pragma unroll
        for (int c = 0; c < CV; ++c) {
          float pvv = maskv ? vr[c] : rec[c];
          pn[o + c] = pvv;
          mn2[o + c] = fmaf(gn, pvv, ogn * mvc[(long)qg * CV + c - (long)0] * 0.f
                                      + ogn * mvs[i & 1][o + c] * 0.f
                                      + ogn * mvs[i & 1][o + c]);
        }
      }
    }

    // -------- A-phase: kh convert (i+2) + m_kh EMA (i+1), rows [q0,+32) --------
    if (i + 2 < SEQ) {
      const int pl = tid >> 4, sc = tid & 15;
      const int p = q0 + pl;
      cvt16(k + ((long)(lb * SEQ + i + 2) * HW + p) * CK + sc * 16,
            khs[(i + 2) % 3] + ((long)lb * HW + p) * CK + sc * 16);
    }
    if (i + 1 < STEPS) {
      const int pl = tid >> 4, sc = tid & 15;
      const int p = q0 + pl;
      float a = att[(long)(lb * SEQ + i + 1) * HW + p];
      float g = 1.0f / (1.0f + __expf(-a)), og = 1.0f - g;
      long off = ((long)lb * HW + p) * CK + sc * 16;
      const u16* kr = khs[(i + 1) % 3] + off;
      const u16* mo = mkhs[i & 1] + off;
      u16* mnp = mkhs[(i + 1) & 1] + off;
      int4 kv[2], mv4[2];
      kv[0] = *(const int4*)kr; kv[1] = *(const int4*)(kr + 8);
      mv4[0] = *(const int4*)mo; mv4[1] = *(const int4*)(mo + 8);
      const u16* ku = (const u16*)kv;
      const u16* mu = (const u16*)mv4;
      u16 nh[16];
      #pragma unroll
      for (int j = 0; j < 16; ++j)
        nh[j] = f2h(fmaf(g, h2f(ku[j]), og * h2f(mu[j])));
      *(int4*)mnp = *(const int4*)nh;
      *(int4*)(mnp + 8) = *(const int4*)(nh + 8);
    }

    gsync(bar, bar + 1, lg); lg++;
  }
}

extern "C" void kernel_launch(void* const* d_in, const int* in_sizes, int n_in,
                              void* d_out, int out_size, void* d_ws, size_t ws_size,
                              hipStream_t stream) {
  const float* k   = (const float*)d_in[0];
  const float* v   = (const float*)d_in[1];
  const float* att = (const float*)d_in[2];
  const int* seq_mask = (const int*)d_in[3];
  float* out = (float*)d_out;
  char* ws = (char*)d_ws;   // needs 21.4 MB; observed ws is 512 MB (R5/R6 fills)

  init_bar<<<1, 1, 0, stream>>>((unsigned*)(ws + BAR_OFF));

  void* kargs[] = {(void*)&k, (void*)&v, (void*)&att,
                   (void*)&seq_mask, (void*)&out, (void*)&ws};
  hipLaunchCooperativeKernel((void*)mega, dim3(NBLK), dim3(512), kargs, 0, stream);
}